// Round 1
// baseline (219.079 us; speedup 1.0000x reference)
//
#include <hip/hip_runtime.h>

#define D 128
#define TN 64        // nodes per block
#define BK 32        // k-tile
#define XS (D + 4)   // smem_x row stride (floats)
#define WS (D + 4)   // smem_w row stride (floats)

__device__ __forceinline__ unsigned short f2bf(float f) {
    unsigned int u = __float_as_uint(f);
    u += 0x7FFFu + ((u >> 16) & 1u);   // round-to-nearest-even
    return (unsigned short)(u >> 16);
}
__device__ __forceinline__ float bflo(int u) {
    return __uint_as_float(((unsigned int)u) << 16);
}
__device__ __forceinline__ float bfhi(int u) {
    return __uint_as_float(((unsigned int)u) & 0xFFFF0000u);
}

// gridDim.y == 2: y=0 -> lin1 path, fold bilinear W -> G1 table (bf16)
//                 y=1 -> lin2 path -> H2 table (bf16)
__global__ __launch_bounds__(256) void node_kernel(
    const float* __restrict__ z,
    const float* __restrict__ lin1_w, const float* __restrict__ lin1_b,
    const float* __restrict__ lin2_w, const float* __restrict__ lin2_b,
    const float* __restrict__ bil_w,
    const float* __restrict__ norm_w, const float* __restrict__ norm_b,
    unsigned short* __restrict__ g1, unsigned short* __restrict__ h2tab,
    int N)
{
    __shared__ float sx[TN][XS];
    __shared__ float sw[BK][WS];

    const int tid  = threadIdx.x;
    const int mode = blockIdx.y;                  // block-uniform
    const float* lw = (mode == 0) ? lin1_w : lin2_w;
    const float* lb = (mode == 0) ? lin1_b : lin2_b;
    const int n0 = blockIdx.x * TN;

    // ---- phase 1: load z rows, LayerNorm -> sx (zn) ----
    const int wave = tid >> 6;
    const int lane = tid & 63;
    for (int rr = wave; rr < TN; rr += 4) {
        int n  = n0 + rr;
        int nc = (n < N) ? n : (N - 1);
        float2 v = *reinterpret_cast<const float2*>(z + (size_t)nc * D + lane * 2);
        float s = v.x + v.y;
        float q = v.x * v.x + v.y * v.y;
        #pragma unroll
        for (int m = 32; m >= 1; m >>= 1) {
            s += __shfl_xor(s, m, 64);
            q += __shfl_xor(q, m, 64);
        }
        float mu  = s * (1.0f / D);
        float var = q * (1.0f / D) - mu * mu;
        float rs  = rsqrtf(var + 1e-5f);
        float2 nwv = *reinterpret_cast<const float2*>(norm_w + lane * 2);
        float2 nbv = *reinterpret_cast<const float2*>(norm_b + lane * 2);
        sx[rr][lane * 2 + 0] = (v.x - mu) * rs * nwv.x + nbv.x;
        sx[rr][lane * 2 + 1] = (v.y - mu) * rs * nwv.y + nbv.y;
    }
    __syncthreads();

    const int r0 = (tid >> 5) * 8;    // 8 rows per thread
    const int f0 = (tid & 31) * 4;    // 4 features per thread

    // ---- GEMM1: acc[r][f] = sum_k zn[r][k] * lw[f][k] ----
    float acc[8][4];
    #pragma unroll
    for (int i = 0; i < 8; ++i)
        #pragma unroll
        for (int c = 0; c < 4; ++c) acc[i][c] = 0.0f;

    for (int kb = 0; kb < D / BK; ++kb) {
        const int k0 = kb * BK;
        {   // stage W[f][k0..k0+31] transposed into sw[kk][f]
            int fbase = tid >> 3;            // 0..31
            int kk = (tid & 7) * 4;
            #pragma unroll
            for (int j = 0; j < 4; ++j) {
                int f = fbase + j * 32;
                float4 wv = *reinterpret_cast<const float4*>(lw + (size_t)f * D + k0 + kk);
                sw[kk + 0][f] = wv.x;
                sw[kk + 1][f] = wv.y;
                sw[kk + 2][f] = wv.z;
                sw[kk + 3][f] = wv.w;
            }
        }
        __syncthreads();
        #pragma unroll
        for (int kk = 0; kk < BK; ++kk) {
            float4 wv = *reinterpret_cast<const float4*>(&sw[kk][f0]);
            #pragma unroll
            for (int i = 0; i < 8; ++i) {
                float xv = sx[r0 + i][k0 + kk];
                acc[i][0] += xv * wv.x;
                acc[i][1] += xv * wv.y;
                acc[i][2] += xv * wv.z;
                acc[i][3] += xv * wv.w;
            }
        }
        __syncthreads();
    }

    // ---- epilogue: bias + relu + LayerNorm (row stats over 32-lane group) ----
    float4 bv  = *reinterpret_cast<const float4*>(lb + f0);
    float4 nwv = *reinterpret_cast<const float4*>(norm_w + f0);
    float4 nbv = *reinterpret_cast<const float4*>(norm_b + f0);
    float h[8][4];
    #pragma unroll
    for (int i = 0; i < 8; ++i) {
        float a0v = fmaxf(acc[i][0] + bv.x, 0.0f);
        float a1v = fmaxf(acc[i][1] + bv.y, 0.0f);
        float a2v = fmaxf(acc[i][2] + bv.z, 0.0f);
        float a3v = fmaxf(acc[i][3] + bv.w, 0.0f);
        float s = a0v + a1v + a2v + a3v;
        float q = a0v * a0v + a1v * a1v + a2v * a2v + a3v * a3v;
        #pragma unroll
        for (int m = 16; m >= 1; m >>= 1) {
            s += __shfl_xor(s, m, 64);
            q += __shfl_xor(q, m, 64);
        }
        float mu  = s * (1.0f / D);
        float var = q * (1.0f / D) - mu * mu;
        float rs  = rsqrtf(var + 1e-5f);
        h[i][0] = (a0v - mu) * rs * nwv.x + nbv.x;
        h[i][1] = (a1v - mu) * rs * nwv.y + nbv.y;
        h[i][2] = (a2v - mu) * rs * nwv.z + nbv.z;
        h[i][3] = (a3v - mu) * rs * nwv.w + nbv.w;
    }

    if (mode == 1) {
        // write H2 table (bf16)
        #pragma unroll
        for (int i = 0; i < 8; ++i) {
            int n = n0 + r0 + i;
            if (n < N) {
                ushort4 o = make_ushort4(f2bf(h[i][0]), f2bf(h[i][1]),
                                         f2bf(h[i][2]), f2bf(h[i][3]));
                *reinterpret_cast<ushort4*>(h2tab + (size_t)n * D + f0) = o;
            }
        }
        return;
    }

    // ---- mode 0: GEMM2 G1 = H1 @ bil_w  (out[r][f] = sum_d h[r][d]*Wb[d][f]) ----
    // overwrite sx with h
    #pragma unroll
    for (int i = 0; i < 8; ++i) {
        float4 hv = make_float4(h[i][0], h[i][1], h[i][2], h[i][3]);
        *reinterpret_cast<float4*>(&sx[r0 + i][f0]) = hv;
    }
    __syncthreads();

    float acc2[8][4];
    #pragma unroll
    for (int i = 0; i < 8; ++i)
        #pragma unroll
        for (int c = 0; c < 4; ++c) acc2[i][c] = 0.0f;

    for (int kb = 0; kb < D / BK; ++kb) {
        const int k0 = kb * BK;
        {   // stage Wb[k0..k0+31][f] (natural layout, fully coalesced)
            int krow = tid >> 5;             // 0..7
            int fl   = (tid & 31) * 4;
            #pragma unroll
            for (int j = 0; j < 4; ++j) {
                int k = k0 + krow + j * 8;
                float4 wv = *reinterpret_cast<const float4*>(bil_w + (size_t)k * D + fl);
                *reinterpret_cast<float4*>(&sw[krow + j * 8][fl]) = wv;
            }
        }
        __syncthreads();
        #pragma unroll
        for (int kk = 0; kk < BK; ++kk) {
            float4 wv = *reinterpret_cast<const float4*>(&sw[kk][f0]);
            #pragma unroll
            for (int i = 0; i < 8; ++i) {
                float xv = sx[r0 + i][k0 + kk];
                acc2[i][0] += xv * wv.x;
                acc2[i][1] += xv * wv.y;
                acc2[i][2] += xv * wv.z;
                acc2[i][3] += xv * wv.w;
            }
        }
        __syncthreads();
    }

    #pragma unroll
    for (int i = 0; i < 8; ++i) {
        int n = n0 + r0 + i;
        if (n < N) {
            ushort4 o = make_ushort4(f2bf(acc2[i][0]), f2bf(acc2[i][1]),
                                     f2bf(acc2[i][2]), f2bf(acc2[i][3]));
            *reinterpret_cast<ushort4*>(g1 + (size_t)n * D + f0) = o;
        }
    }
}

// score[e] = dot(G1[a0], H2[a1]) + bil_b ; 16 lanes per arc, 8 bf16 each
__global__ __launch_bounds__(256) void arc_kernel(
    const int* __restrict__ arcs,
    const unsigned short* __restrict__ g1,
    const unsigned short* __restrict__ h2,
    const float* __restrict__ bil_b,
    float* __restrict__ out, int E)
{
    long long gid = (long long)blockIdx.x * blockDim.x + threadIdx.x;
    int e = (int)(gid >> 4);
    int s = (int)(gid & 15);
    if (e >= E) return;

    int a0 = arcs[2 * e + 0];
    int a1 = arcs[2 * e + 1];

    const int4 pv = *reinterpret_cast<const int4*>(g1 + (size_t)a0 * D + s * 8);
    const int4 qv = *reinterpret_cast<const int4*>(h2 + (size_t)a1 * D + s * 8);

    float acc = 0.0f;
    acc += bflo(pv.x) * bflo(qv.x) + bfhi(pv.x) * bfhi(qv.x);
    acc += bflo(pv.y) * bflo(qv.y) + bfhi(pv.y) * bfhi(qv.y);
    acc += bflo(pv.z) * bflo(qv.z) + bfhi(pv.z) * bfhi(qv.z);
    acc += bflo(pv.w) * bflo(qv.w) + bfhi(pv.w) * bfhi(qv.w);

    #pragma unroll
    for (int m = 8; m >= 1; m >>= 1) acc += __shfl_xor(acc, m, 64);

    if (s == 0) out[e] = acc + bil_b[0];
}

extern "C" void kernel_launch(void* const* d_in, const int* in_sizes, int n_in,
                              void* d_out, int out_size, void* d_ws, size_t ws_size,
                              hipStream_t stream) {
    const float* z      = (const float*)d_in[0];
    const int*   arcs   = (const int*)d_in[1];
    const float* lin1_w = (const float*)d_in[2];
    const float* lin1_b = (const float*)d_in[3];
    const float* lin2_w = (const float*)d_in[4];
    const float* lin2_b = (const float*)d_in[5];
    const float* bil_w  = (const float*)d_in[6];
    const float* bil_b  = (const float*)d_in[7];
    const float* norm_w = (const float*)d_in[8];
    const float* norm_b = (const float*)d_in[9];
    float* out = (float*)d_out;

    const int N = in_sizes[0] / D;
    const int E = in_sizes[1] / 2;

    unsigned short* g1 = (unsigned short*)d_ws;
    unsigned short* h2 = g1 + (size_t)N * D;

    dim3 grid1((N + TN - 1) / TN, 2);
    node_kernel<<<grid1, 256, 0, stream>>>(z, lin1_w, lin1_b, lin2_w, lin2_b,
                                           bil_w, norm_w, norm_b, g1, h2, N);

    long long tthreads = (long long)E * 16;
    int blocks = (int)((tthreads + 255) / 256);
    arc_kernel<<<blocks, 256, 0, stream>>>(arcs, g1, h2, bil_b, out, E);
}

// Round 2
// 144.625 us; speedup vs baseline: 1.5148x; 1.5148x over previous
//
#include <hip/hip_runtime.h>

#define D 128
#define TM 64

typedef __attribute__((ext_vector_type(8))) short short8v;
typedef __attribute__((ext_vector_type(4))) float float4v;

__device__ __forceinline__ unsigned short f2bf(float f) {
    unsigned int u = __float_as_uint(f);
    u += 0x7FFFu + ((u >> 16) & 1u);   // round-to-nearest-even
    return (unsigned short)(u >> 16);
}
__device__ __forceinline__ float bflo(int u) {
    return __uint_as_float(((unsigned int)u) << 16);
}
__device__ __forceinline__ float bfhi(int u) {
    return __uint_as_float(((unsigned int)u) & 0xFFFF0000u);
}

// Convert 3 weight matrices (each [128][128] fp32, row-major [n][k]) into
// bf16 MFMA B-fragment order: dst[((t*4+ks)*64 + lane)*8 + j] = W[t*16+(lane&15)][ks*32+(lane>>4)*8+j]
__global__ __launch_bounds__(256) void wconv(
    const float* __restrict__ w1, const float* __restrict__ w2,
    const float* __restrict__ wb, unsigned short* __restrict__ dst)
{
    int tid = blockIdx.x * 256 + threadIdx.x;   // 0..6143
    int w = tid >> 11;          // which weight
    int r = tid & 2047;         // (t*4+ks)*64 + lane
    int l = r & 63;
    int tk = r >> 6;            // t*4+ks
    int t = tk >> 2, ks = tk & 3;
    int n = t * 16 + (l & 15);
    int k = ks * 32 + (l >> 4) * 8;
    const float* src = (w == 0) ? w1 : (w == 1) ? w2 : wb;
    const float* p = src + n * D + k;
    float4 a = *(const float4*)p;
    float4 b = *(const float4*)(p + 4);
    union { int4 i4; unsigned short u[8]; } pk;
    pk.u[0] = f2bf(a.x); pk.u[1] = f2bf(a.y); pk.u[2] = f2bf(a.z); pk.u[3] = f2bf(a.w);
    pk.u[4] = f2bf(b.x); pk.u[5] = f2bf(b.y); pk.u[6] = f2bf(b.z); pk.u[7] = f2bf(b.w);
    *(int4*)(dst + (size_t)tid * 8) = pk.i4;
}

// Fused node kernel: per block of 64 nodes:
//   zn = LN(z)                       -> LDS sa (bf16)
//   H1 = LN(relu(zn@W1^T+b1))        -> T1 (GEMM1, LN epilogue)
//   H2 = LN(relu(zn@W2^T+b2))        -> LDS sh (GEMM2)
//   T2 = H2 @ Wb^T                   -> T2 (GEMM3)
// score[e] = dot(T1[a0], T2[a1]) + bb  (arc kernel)
__global__ __launch_bounds__(256) void node_kernel(
    const float* __restrict__ z,
    const unsigned short* __restrict__ wfrag,
    const float* __restrict__ lin1_b, const float* __restrict__ lin2_b,
    const float* __restrict__ norm_w, const float* __restrict__ norm_b,
    unsigned short* __restrict__ T1, unsigned short* __restrict__ T2,
    int N)
{
    __shared__ unsigned short sa[TM][136];   // +8 shorts pad: 2-way (free) bank pattern
    __shared__ unsigned short sh[TM][136];

    const int tid  = threadIdx.x;
    const int lane = tid & 63;
    const int wave = tid >> 6;
    const int n0   = blockIdx.x * TM;
    const int cg   = lane & 15;
    const int q    = lane >> 4;

    // ---- phase 1: LN(z) -> sa (bf16) ----
    {
        const int c = cg * 8;
        float4 nw0 = *(const float4*)(norm_w + c);
        float4 nw1 = *(const float4*)(norm_w + c + 4);
        float4 nb0 = *(const float4*)(norm_b + c);
        float4 nb1 = *(const float4*)(norm_b + c + 4);
        #pragma unroll
        for (int it = 0; it < 4; ++it) {
            int rr = wave * 16 + it * 4 + q;
            int n  = n0 + rr;
            int nc = (n < N) ? n : (N - 1);
            const float* zp = z + (size_t)nc * D + c;
            float4 v0 = *(const float4*)zp;
            float4 v1 = *(const float4*)(zp + 4);
            float s  = v0.x + v0.y + v0.z + v0.w + v1.x + v1.y + v1.z + v1.w;
            float qq = v0.x*v0.x + v0.y*v0.y + v0.z*v0.z + v0.w*v0.w
                     + v1.x*v1.x + v1.y*v1.y + v1.z*v1.z + v1.w*v1.w;
            #pragma unroll
            for (int m = 1; m <= 8; m <<= 1) {
                s  += __shfl_xor(s, m, 64);
                qq += __shfl_xor(qq, m, 64);
            }
            float mu  = s * (1.0f / D);
            float var = qq * (1.0f / D) - mu * mu;
            float rs  = rsqrtf(var + 1e-5f);
            union { int4 i4; unsigned short u[8]; } pk;
            pk.u[0] = f2bf((v0.x - mu) * rs * nw0.x + nb0.x);
            pk.u[1] = f2bf((v0.y - mu) * rs * nw0.y + nb0.y);
            pk.u[2] = f2bf((v0.z - mu) * rs * nw0.z + nb0.z);
            pk.u[3] = f2bf((v0.w - mu) * rs * nw0.w + nb0.w);
            pk.u[4] = f2bf((v1.x - mu) * rs * nw1.x + nb1.x);
            pk.u[5] = f2bf((v1.y - mu) * rs * nw1.y + nb1.y);
            pk.u[6] = f2bf((v1.z - mu) * rs * nw1.z + nb1.z);
            pk.u[7] = f2bf((v1.w - mu) * rs * nw1.w + nb1.w);
            *(int4*)&sa[rr][c] = pk.i4;
        }
    }
    __syncthreads();

    float4v acc[8];

    // GEMM over A (LDS tile) x B (global frags): wave computes 16 rows x 128 cols
    auto run_gemm = [&](const unsigned short (*A)[136], const unsigned short* wf) {
        #pragma unroll
        for (int t = 0; t < 8; ++t) acc[t] = (float4v)(0.0f);
        #pragma unroll
        for (int ks = 0; ks < 4; ++ks) {
            short8v a = *(const short8v*)&A[wave * 16 + cg][ks * 32 + q * 8];
            const short8v* wp = (const short8v*)wf + ks * 64 + lane;
            #pragma unroll
            for (int t = 0; t < 8; ++t) {
                short8v b = wp[t * 256];   // ((t*4+ks)*64 + lane)
                acc[t] = __builtin_amdgcn_mfma_f32_16x16x32_bf16(a, b, acc[t], 0, 0, 0);
            }
        }
    };

    // bias + relu + LN epilogue on acc (C-layout: col=t*16+cg, row=wave*16+q*4+i) -> sh
    auto epilogue_ln = [&](const float* lb) {
        float bia[8], nwv[8], nbv[8];
        #pragma unroll
        for (int t = 0; t < 8; ++t) {
            int col = t * 16 + cg;
            bia[t] = lb[col]; nwv[t] = norm_w[col]; nbv[t] = norm_b[col];
        }
        float s[4] = {0, 0, 0, 0}, qs[4] = {0, 0, 0, 0};
        #pragma unroll
        for (int t = 0; t < 8; ++t)
            #pragma unroll
            for (int i = 0; i < 4; ++i) {
                float v = fmaxf(acc[t][i] + bia[t], 0.0f);
                acc[t][i] = v;
                s[i] += v; qs[i] += v * v;
            }
        #pragma unroll
        for (int i = 0; i < 4; ++i) {
            #pragma unroll
            for (int m = 1; m <= 8; m <<= 1) {
                s[i]  += __shfl_xor(s[i], m, 64);
                qs[i] += __shfl_xor(qs[i], m, 64);
            }
        }
        #pragma unroll
        for (int i = 0; i < 4; ++i) {
            float mu  = s[i] * (1.0f / D);
            float var = qs[i] * (1.0f / D) - mu * mu;
            float rs  = rsqrtf(var + 1e-5f);
            s[i] = mu; qs[i] = rs;
        }
        #pragma unroll
        for (int t = 0; t < 8; ++t)
            #pragma unroll
            for (int i = 0; i < 4; ++i)
                sh[wave * 16 + q * 4 + i][t * 16 + cg] =
                    f2bf((acc[t][i] - s[i]) * qs[i] * nwv[t] + nbv[t]);
    };

    // coalesced LDS -> global bf16 copy (64 rows x 128)
    auto copyout = [&](const unsigned short (*S)[136], unsigned short* dst) {
        int r = tid >> 2;
        int n = n0 + r;
        if (n < N) {
            #pragma unroll
            for (int j = 0; j < 4; ++j) {
                int c = (tid & 3) * 8 + j * 32;
                int4 d = *(const int4*)&S[r][c];
                *(int4*)(dst + (size_t)n * D + c) = d;
            }
        }
    };

    // ---- GEMM1: H1 ----
    run_gemm(sa, wfrag);
    epilogue_ln(lin1_b);            // writes sh
    __syncthreads();
    copyout(sh, T1);                // reads sh

    // ---- GEMM2: H2 ----
    run_gemm(sa, wfrag + 16384);
    __syncthreads();                // copyout reads of sh done before overwrite
    epilogue_ln(lin2_b);            // writes sh (h2)
    __syncthreads();

    // ---- GEMM3: T2 = H2 @ Wb^T (no bias/LN) ----
    run_gemm(sh, wfrag + 32768);
    #pragma unroll
    for (int t = 0; t < 8; ++t)
        #pragma unroll
        for (int i = 0; i < 4; ++i)
            sa[wave * 16 + q * 4 + i][t * 16 + cg] = f2bf(acc[t][i]);
    __syncthreads();
    copyout(sa, T2);
}

// score[e] = dot(T1[a0], T2[a1]) + bb ; 8 lanes/arc, wave handles 8 arcs
__global__ __launch_bounds__(256) void arc_kernel(
    const int* __restrict__ arcs,
    const unsigned short* __restrict__ T1,
    const unsigned short* __restrict__ T2,
    const float* __restrict__ bil_b,
    float* __restrict__ out, int E)
{
    const int tid  = threadIdx.x;
    const int lane = tid & 63;
    long long gw = ((long long)blockIdx.x * 256 + tid) >> 6;   // global wave id
    long long e0 = gw * 8;
    int aidx = lane >> 3;          // arc within wave (0..7)
    int s    = lane & 7;           // lane within arc

    long long ii = e0 * 2 + (lane & 15);
    long long iimax = (long long)E * 2 - 1;
    int iv = arcs[ii <= iimax ? ii : iimax];
    int a0 = __shfl(iv, aidx * 2, 64);
    int a1 = __shfl(iv, aidx * 2 + 1, 64);
    long long e = e0 + aidx;

    const int4* P = (const int4*)(T1 + (size_t)a0 * D);
    const int4* Q = (const int4*)(T2 + (size_t)a1 * D);
    int4 x0 = P[s];
    int4 x1 = P[s + 8];
    int4 y0 = Q[s];
    int4 y1 = Q[s + 8];

    float acc = 0.0f;
    acc += bflo(x0.x) * bflo(y0.x) + bfhi(x0.x) * bfhi(y0.x);
    acc += bflo(x0.y) * bflo(y0.y) + bfhi(x0.y) * bfhi(y0.y);
    acc += bflo(x0.z) * bflo(y0.z) + bfhi(x0.z) * bfhi(y0.z);
    acc += bflo(x0.w) * bflo(y0.w) + bfhi(x0.w) * bfhi(y0.w);
    acc += bflo(x1.x) * bflo(y1.x) + bfhi(x1.x) * bfhi(y1.x);
    acc += bflo(x1.y) * bflo(y1.y) + bfhi(x1.y) * bfhi(y1.y);
    acc += bflo(x1.z) * bflo(y1.z) + bfhi(x1.z) * bfhi(y1.z);
    acc += bflo(x1.w) * bflo(y1.w) + bfhi(x1.w) * bfhi(y1.w);

    #pragma unroll
    for (int m = 1; m <= 4; m <<= 1) acc += __shfl_xor(acc, m, 64);

    if (s == 0 && e < E) out[e] = acc + bil_b[0];
}

extern "C" void kernel_launch(void* const* d_in, const int* in_sizes, int n_in,
                              void* d_out, int out_size, void* d_ws, size_t ws_size,
                              hipStream_t stream) {
    const float* z      = (const float*)d_in[0];
    const int*   arcs   = (const int*)d_in[1];
    const float* lin1_w = (const float*)d_in[2];
    const float* lin1_b = (const float*)d_in[3];
    const float* lin2_w = (const float*)d_in[4];
    const float* lin2_b = (const float*)d_in[5];
    const float* bil_w  = (const float*)d_in[6];
    const float* bil_b  = (const float*)d_in[7];
    const float* norm_w = (const float*)d_in[8];
    const float* norm_b = (const float*)d_in[9];
    float* out = (float*)d_out;

    const int N = in_sizes[0] / D;
    const int E = in_sizes[1] / 2;

    unsigned short* wfrag = (unsigned short*)d_ws;          // 3 * 16384 shorts
    unsigned short* T1 = wfrag + 3 * 16384;
    unsigned short* T2 = T1 + (size_t)N * D;

    wconv<<<24, 256, 0, stream>>>(lin1_w, lin2_w, bil_w, wfrag);

    node_kernel<<<(N + TM - 1) / TM, 256, 0, stream>>>(
        z, wfrag, lin1_b, lin2_b, norm_w, norm_b, T1, T2, N);

    long long waves = ((long long)E + 7) / 8;
    int blocks = (int)((waves + 3) / 4);
    arc_kernel<<<blocks, 256, 0, stream>>>(arcs, T1, T2, bil_b, out, E);
}

// Round 3
// 141.946 us; speedup vs baseline: 1.5434x; 1.0189x over previous
//
#include <hip/hip_runtime.h>

#define D 128
#define TM 64

typedef __attribute__((ext_vector_type(8))) short short8v;
typedef __attribute__((ext_vector_type(4))) float float4v;

__device__ __forceinline__ unsigned short f2bf(float f) {
    unsigned int u = __float_as_uint(f);
    u += 0x7FFFu + ((u >> 16) & 1u);   // round-to-nearest-even
    return (unsigned short)(u >> 16);
}
__device__ __forceinline__ float bflo(int u) {
    return __uint_as_float(((unsigned int)u) << 16);
}
__device__ __forceinline__ float bfhi(int u) {
    return __uint_as_float(((unsigned int)u) & 0xFFFF0000u);
}

// Convert 3 weight matrices (each [128][128] fp32, row-major [n][k]) into
// bf16 MFMA B-fragment order:
// dst[((t*4+ks)*64 + lane)*8 + j] = W[t*16+(lane&15)][ks*32+(lane>>4)*8+j]
__global__ __launch_bounds__(256) void wconv(
    const float* __restrict__ w1, const float* __restrict__ w2,
    const float* __restrict__ wb, unsigned short* __restrict__ dst)
{
    int tid = blockIdx.x * 256 + threadIdx.x;   // 0..6143
    int w = tid >> 11;          // which weight
    int r = tid & 2047;         // (t*4+ks)*64 + lane
    int l = r & 63;
    int tk = r >> 6;            // t*4+ks
    int t = tk >> 2, ks = tk & 3;
    int n = t * 16 + (l & 15);
    int k = ks * 32 + (l >> 4) * 8;
    const float* src = (w == 0) ? w1 : (w == 1) ? w2 : wb;
    const float* p = src + n * D + k;
    float4 a = *(const float4*)p;
    float4 b = *(const float4*)(p + 4);
    union { int4 i4; unsigned short u[8]; } pk;
    pk.u[0] = f2bf(a.x); pk.u[1] = f2bf(a.y); pk.u[2] = f2bf(a.z); pk.u[3] = f2bf(a.w);
    pk.u[4] = f2bf(b.x); pk.u[5] = f2bf(b.y); pk.u[6] = f2bf(b.z); pk.u[7] = f2bf(b.w);
    *(int4*)(dst + (size_t)tid * 8) = pk.i4;
}

// Fused node kernel, BARRIER-FREE: each wave owns rows [wave*16, wave*16+16)
// of every LDS buffer; no cross-wave LDS sharing, so no __syncthreads needed.
//   zn = LN(z)                  -> sa (bf16)
//   GEMM1+GEMM2 fused (dual acc): H1 pre-LN, H2 pre-LN
//   ep1: bias+relu+LN -> sh1 -> T1 ; ep2 -> sh2
//   GEMM3: T2 = H2 @ Wb^T  -> sa -> T2
__global__ __launch_bounds__(256) void node_kernel(
    const float* __restrict__ z,
    const unsigned short* __restrict__ wfrag,
    const float* __restrict__ lin1_b, const float* __restrict__ lin2_b,
    const float* __restrict__ norm_w, const float* __restrict__ norm_b,
    unsigned short* __restrict__ T1, unsigned short* __restrict__ T2,
    int N)
{
    __shared__ unsigned short sa [TM][136];
    __shared__ unsigned short sh1[TM][136];
    __shared__ unsigned short sh2[TM][136];

    const int tid   = threadIdx.x;
    const int lane  = tid & 63;
    const int wave  = tid >> 6;
    const int n0    = blockIdx.x * TM;
    const int cg    = lane & 15;
    const int q     = lane >> 4;
    const int rbase = wave * 16;

    // ---- phase 1: LN(z) -> sa (own 16 rows) ----
    {
        const int c = cg * 8;
        float4 nw0 = *(const float4*)(norm_w + c);
        float4 nw1 = *(const float4*)(norm_w + c + 4);
        float4 nb0 = *(const float4*)(norm_b + c);
        float4 nb1 = *(const float4*)(norm_b + c + 4);
        #pragma unroll
        for (int it = 0; it < 4; ++it) {
            int rr = rbase + it * 4 + q;
            int n  = n0 + rr;
            int nc = (n < N) ? n : (N - 1);
            const float* zp = z + (size_t)nc * D + c;
            float4 v0 = *(const float4*)zp;
            float4 v1 = *(const float4*)(zp + 4);
            float s  = v0.x + v0.y + v0.z + v0.w + v1.x + v1.y + v1.z + v1.w;
            float qq = v0.x*v0.x + v0.y*v0.y + v0.z*v0.z + v0.w*v0.w
                     + v1.x*v1.x + v1.y*v1.y + v1.z*v1.z + v1.w*v1.w;
            #pragma unroll
            for (int m = 1; m <= 8; m <<= 1) {
                s  += __shfl_xor(s, m, 64);
                qq += __shfl_xor(qq, m, 64);
            }
            float mu  = s * (1.0f / D);
            float var = qq * (1.0f / D) - mu * mu;
            float rs  = rsqrtf(var + 1e-5f);
            union { int4 i4; unsigned short u[8]; } pk;
            pk.u[0] = f2bf((v0.x - mu) * rs * nw0.x + nb0.x);
            pk.u[1] = f2bf((v0.y - mu) * rs * nw0.y + nb0.y);
            pk.u[2] = f2bf((v0.z - mu) * rs * nw0.z + nb0.z);
            pk.u[3] = f2bf((v0.w - mu) * rs * nw0.w + nb0.w);
            pk.u[4] = f2bf((v1.x - mu) * rs * nw1.x + nb1.x);
            pk.u[5] = f2bf((v1.y - mu) * rs * nw1.y + nb1.y);
            pk.u[6] = f2bf((v1.z - mu) * rs * nw1.z + nb1.z);
            pk.u[7] = f2bf((v1.w - mu) * rs * nw1.w + nb1.w);
            *(int4*)&sa[rr][c] = pk.i4;
        }
    }

    // ---- GEMM1 + GEMM2 fused (dual accumulators) ----
    float4v acc1[8], acc2[8];
    #pragma unroll
    for (int t = 0; t < 8; ++t) { acc1[t] = (float4v)(0.0f); acc2[t] = (float4v)(0.0f); }
    #pragma unroll
    for (int ks = 0; ks < 4; ++ks) {
        short8v a = *(const short8v*)&sa[rbase + cg][ks * 32 + q * 8];
        const short8v* wp = (const short8v*)wfrag + ks * 64 + lane;
        #pragma unroll
        for (int t = 0; t < 8; ++t) {
            acc1[t] = __builtin_amdgcn_mfma_f32_16x16x32_bf16(a, wp[t * 256],        acc1[t], 0, 0, 0);
            acc2[t] = __builtin_amdgcn_mfma_f32_16x16x32_bf16(a, wp[t * 256 + 2048], acc2[t], 0, 0, 0);
        }
    }

    // bias+relu+LN epilogue (C-layout: col=t*16+cg, row=rbase+q*4+i) -> dst
    auto epilogue = [&](float4v* acc, const float* lb, unsigned short (*dst)[136]) {
        float s[4] = {0, 0, 0, 0}, qs[4] = {0, 0, 0, 0};
        #pragma unroll
        for (int t = 0; t < 8; ++t) {
            float b = lb[t * 16 + cg];
            #pragma unroll
            for (int i = 0; i < 4; ++i) {
                float v = fmaxf(acc[t][i] + b, 0.0f);
                acc[t][i] = v;
                s[i] += v; qs[i] += v * v;
            }
        }
        #pragma unroll
        for (int i = 0; i < 4; ++i) {
            #pragma unroll
            for (int m = 1; m <= 8; m <<= 1) {
                s[i]  += __shfl_xor(s[i], m, 64);
                qs[i] += __shfl_xor(qs[i], m, 64);
            }
            float mu  = s[i] * (1.0f / D);
            float var = qs[i] * (1.0f / D) - mu * mu;
            s[i] = mu; qs[i] = rsqrtf(var + 1e-5f);
        }
        #pragma unroll
        for (int t = 0; t < 8; ++t) {
            int col = t * 16 + cg;
            float nw = norm_w[col], nb = norm_b[col];
            #pragma unroll
            for (int i = 0; i < 4; ++i)
                dst[rbase + q * 4 + i][col] = f2bf((acc[t][i] - s[i]) * qs[i] * nw + nb);
        }
    };

    // coalesced LDS -> global bf16 copy of own 16 rows
    auto copyout = [&](const unsigned short (*S)[136], unsigned short* dst) {
        int r = rbase + (lane >> 2);
        int n = n0 + r;
        if (n < N) {
            #pragma unroll
            for (int j = 0; j < 4; ++j) {
                int c = (lane & 3) * 8 + j * 32;
                *(int4*)(dst + (size_t)n * D + c) = *(const int4*)&S[r][c];
            }
        }
    };

    epilogue(acc1, lin1_b, sh1);
    epilogue(acc2, lin2_b, sh2);
    copyout(sh1, T1);

    // ---- GEMM3: T2 = H2 @ Wb^T ----
    #pragma unroll
    for (int t = 0; t < 8; ++t) acc1[t] = (float4v)(0.0f);
    #pragma unroll
    for (int ks = 0; ks < 4; ++ks) {
        short8v a = *(const short8v*)&sh2[rbase + cg][ks * 32 + q * 8];
        const short8v* wp = (const short8v*)wfrag + 4096 + ks * 64 + lane;
        #pragma unroll
        for (int t = 0; t < 8; ++t)
            acc1[t] = __builtin_amdgcn_mfma_f32_16x16x32_bf16(a, wp[t * 256], acc1[t], 0, 0, 0);
    }
    #pragma unroll
    for (int t = 0; t < 8; ++t)
        #pragma unroll
        for (int i = 0; i < 4; ++i)
            sa[rbase + q * 4 + i][t * 16 + cg] = f2bf(acc1[t][i]);
    copyout(sa, T2);
}

// score[e] = dot(T1[a0], T2[a1]) + bb ; 4 lanes/arc, 16 arcs/wave,
// 8 independent 16B gathers per lane for MLP.
__global__ __launch_bounds__(256) void arc_kernel(
    const int* __restrict__ arcs,
    const unsigned short* __restrict__ T1,
    const unsigned short* __restrict__ T2,
    const float* __restrict__ bil_b,
    float* __restrict__ out, int E)
{
    const int tid  = threadIdx.x;
    const int lane = tid & 63;
    long long gw = ((long long)blockIdx.x * 256 + tid) >> 6;   // global wave id
    long long e0 = gw * 16;
    int aidx = lane >> 2;          // arc within wave (0..15)
    int s    = lane & 3;           // lane within arc

    long long ii = e0 * 2 + (lane & 31);
    long long iimax = (long long)E * 2 - 1;
    int iv = arcs[ii <= iimax ? ii : iimax];
    int a0 = __shfl(iv, aidx * 2, 64);
    int a1 = __shfl(iv, aidx * 2 + 1, 64);
    long long e = e0 + aidx;

    const int4* P = (const int4*)(T1 + (size_t)a0 * D);
    const int4* Q = (const int4*)(T2 + (size_t)a1 * D);
    int4 x0 = P[s];
    int4 x1 = P[s + 4];
    int4 x2 = P[s + 8];
    int4 x3 = P[s + 12];
    int4 y0 = Q[s];
    int4 y1 = Q[s + 4];
    int4 y2 = Q[s + 8];
    int4 y3 = Q[s + 12];

    float acc = 0.0f;
    acc += bflo(x0.x)*bflo(y0.x) + bfhi(x0.x)*bfhi(y0.x);
    acc += bflo(x0.y)*bflo(y0.y) + bfhi(x0.y)*bfhi(y0.y);
    acc += bflo(x0.z)*bflo(y0.z) + bfhi(x0.z)*bfhi(y0.z);
    acc += bflo(x0.w)*bflo(y0.w) + bfhi(x0.w)*bfhi(y0.w);
    acc += bflo(x1.x)*bflo(y1.x) + bfhi(x1.x)*bfhi(y1.x);
    acc += bflo(x1.y)*bflo(y1.y) + bfhi(x1.y)*bfhi(y1.y);
    acc += bflo(x1.z)*bflo(y1.z) + bfhi(x1.z)*bfhi(y1.z);
    acc += bflo(x1.w)*bflo(y1.w) + bfhi(x1.w)*bfhi(y1.w);
    acc += bflo(x2.x)*bflo(y2.x) + bfhi(x2.x)*bfhi(y2.x);
    acc += bflo(x2.y)*bflo(y2.y) + bfhi(x2.y)*bfhi(y2.y);
    acc += bflo(x2.z)*bflo(y2.z) + bfhi(x2.z)*bfhi(y2.z);
    acc += bflo(x2.w)*bflo(y2.w) + bfhi(x2.w)*bfhi(y2.w);
    acc += bflo(x3.x)*bflo(y3.x) + bfhi(x3.x)*bfhi(y3.x);
    acc += bflo(x3.y)*bflo(y3.y) + bfhi(x3.y)*bfhi(y3.y);
    acc += bflo(x3.z)*bflo(y3.z) + bfhi(x3.z)*bfhi(y3.z);
    acc += bflo(x3.w)*bflo(y3.w) + bfhi(x3.w)*bfhi(y3.w);

    acc += __shfl_xor(acc, 1, 64);
    acc += __shfl_xor(acc, 2, 64);

    if (s == 0 && e < E) out[e] = acc + bil_b[0];
}

extern "C" void kernel_launch(void* const* d_in, const int* in_sizes, int n_in,
                              void* d_out, int out_size, void* d_ws, size_t ws_size,
                              hipStream_t stream) {
    const float* z      = (const float*)d_in[0];
    const int*   arcs   = (const int*)d_in[1];
    const float* lin1_w = (const float*)d_in[2];
    const float* lin1_b = (const float*)d_in[3];
    const float* lin2_w = (const float*)d_in[4];
    const float* lin2_b = (const float*)d_in[5];
    const float* bil_w  = (const float*)d_in[6];
    const float* bil_b  = (const float*)d_in[7];
    const float* norm_w = (const float*)d_in[8];
    const float* norm_b = (const float*)d_in[9];
    float* out = (float*)d_out;

    const int N = in_sizes[0] / D;
    const int E = in_sizes[1] / 2;

    unsigned short* wfrag = (unsigned short*)d_ws;          // 3 * 16384 shorts
    unsigned short* T1 = wfrag + 3 * 16384;
    unsigned short* T2 = T1 + (size_t)N * D;

    wconv<<<24, 256, 0, stream>>>(lin1_w, lin2_w, bil_w, wfrag);

    node_kernel<<<(N + TM - 1) / TM, 256, 0, stream>>>(
        z, wfrag, lin1_b, lin2_b, norm_w, norm_b, T1, T2, N);

    long long waves = ((long long)E + 15) / 16;
    int blocks = (int)((waves + 3) / 4);
    arc_kernel<<<blocks, 256, 0, stream>>>(arcs, T1, T2, bil_b, out, E);
}